// Round 5
// baseline (27.665 us; speedup 1.0000x reference)
//
#include <hip/hip_runtime.h>

// hinge one-vs-rest loss:
//   loss = (1/B) * sum_{all elements} max(1 - o*sign(l), 0),  B = 16384
// R4 post-mortem: VGPR=32 proves the compiler sank the loads AGAIN (its
// scheduler minimizes register pressure). Fix: sched_barrier(0) between the
// load block and the compute block -- nothing may cross it, so all 16
// global_load_dwordx4 must issue first and stay live (real 16-deep MLP).

constexpr int BLOCK  = 256;
constexpr int UNROLL = 8;               // float4 per thread per array
constexpr int TILE   = BLOCK * UNROLL;  // 2048 float4 per block

__device__ __forceinline__ float block_reduce(float acc, float* wave_sums) {
    #pragma unroll
    for (int off = 32; off > 0; off >>= 1)
        acc += __shfl_down(acc, off, 64);
    const int lane = threadIdx.x & 63;
    const int wid  = threadIdx.x >> 6;
    if (lane == 0) wave_sums[wid] = acc;
    __syncthreads();
    float s = 0.0f;
    #pragma unroll
    for (int w = 0; w < BLOCK / 64; ++w) s += wave_sums[w];
    return s;
}

// Stage 1 (exact tiling): per-block partials -> d_ws.
__global__ __launch_bounds__(BLOCK) void hinge_stage1_exact(
    const float4* __restrict__ out4,
    const float4* __restrict__ lab4,
    float* __restrict__ partials)
{
    const int tid = threadIdx.x;
    const size_t base = (size_t)blockIdx.x * TILE + tid;
    const float4* __restrict__ po = out4 + base;
    const float4* __restrict__ pl = lab4 + base;

    float4 o[UNROLL], l[UNROLL];
    #pragma unroll
    for (int u = 0; u < UNROLL; ++u) o[u] = po[u * BLOCK];
    #pragma unroll
    for (int u = 0; u < UNROLL; ++u) l[u] = pl[u * BLOCK];

    // Hard scheduling fence: no instruction may cross. Forces all 16 loads
    // to be issued above, with results live in VGPRs -> 16-deep MLP.
    __builtin_amdgcn_sched_barrier(0);

    float a0 = 0.f, a1 = 0.f, a2 = 0.f, a3 = 0.f;
    #pragma unroll
    for (int u = 0; u < UNROLL; ++u) {
        a0 += fmaxf(1.0f - (l[u].x >= 0.0f ? o[u].x : -o[u].x), 0.0f);
        a1 += fmaxf(1.0f - (l[u].y >= 0.0f ? o[u].y : -o[u].y), 0.0f);
        a2 += fmaxf(1.0f - (l[u].z >= 0.0f ? o[u].z : -o[u].z), 0.0f);
        a3 += fmaxf(1.0f - (l[u].w >= 0.0f ? o[u].w : -o[u].w), 0.0f);
    }
    float acc = (a0 + a1) + (a2 + a3);

    __shared__ float wave_sums[BLOCK / 64];
    const float s = block_reduce(acc, wave_sums);
    if (tid == 0) partials[blockIdx.x] = s;
}

// Generic guarded fallback (only if n4 % TILE != 0).
__global__ __launch_bounds__(BLOCK) void hinge_stage1_guarded(
    const float4* __restrict__ out4,
    const float4* __restrict__ lab4,
    float* __restrict__ partials,
    int n4)
{
    const int tid = threadIdx.x;
    const long long base = (long long)blockIdx.x * TILE + tid;
    float acc = 0.0f;
    #pragma unroll
    for (int u = 0; u < UNROLL; ++u) {
        const long long idx = base + (long long)u * BLOCK;
        if (idx < n4) {
            const float4 o = out4[idx];
            const float4 l = lab4[idx];
            acc += fmaxf(1.0f - (l.x >= 0.0f ? o.x : -o.x), 0.0f);
            acc += fmaxf(1.0f - (l.y >= 0.0f ? o.y : -o.y), 0.0f);
            acc += fmaxf(1.0f - (l.z >= 0.0f ? o.z : -o.z), 0.0f);
            acc += fmaxf(1.0f - (l.w >= 0.0f ? o.w : -o.w), 0.0f);
        }
    }
    __shared__ float wave_sums[BLOCK / 64];
    const float s = block_reduce(acc, wave_sums);
    if (tid == 0) partials[blockIdx.x] = s;
}

// Stage 2: one block reduces the partials and writes the scalar loss.
__global__ __launch_bounds__(BLOCK) void hinge_stage2_kernel(
    const float* __restrict__ partials,
    float* __restrict__ loss,
    int n_partials, float inv_b)
{
    float acc = 0.0f;
    for (int i = threadIdx.x; i < n_partials; i += BLOCK)
        acc += partials[i];
    __shared__ float wave_sums[BLOCK / 64];
    const float s = block_reduce(acc, wave_sums);
    if (threadIdx.x == 0) loss[0] = s * inv_b;  // full overwrite
}

extern "C" void kernel_launch(void* const* d_in, const int* in_sizes, int n_in,
                              void* d_out, int out_size, void* d_ws, size_t ws_size,
                              hipStream_t stream) {
    const float* outputs = (const float*)d_in[0];
    const float* labels  = (const float*)d_in[1];
    float* loss     = (float*)d_out;
    float* partials = (float*)d_ws;   // grid floats, written before read

    const long long n = (long long)in_sizes[0];   // 16,384,000
    const int n4 = (int)(n / 4);                  // 4,096,000
    const float inv_b = 1.0f / 16384.0f;

    const int grid = (n4 + TILE - 1) / TILE;      // 2000 blocks

    if (n4 % TILE == 0) {
        hinge_stage1_exact<<<grid, BLOCK, 0, stream>>>(
            (const float4*)outputs, (const float4*)labels, partials);
    } else {
        hinge_stage1_guarded<<<grid, BLOCK, 0, stream>>>(
            (const float4*)outputs, (const float4*)labels, partials, n4);
    }
    hinge_stage2_kernel<<<1, BLOCK, 0, stream>>>(partials, loss, grid, inv_b);
}